// Round 6
// baseline (45.007 us; speedup 1.0000x reference)
//
#include <hip/hip_runtime.h>
#include <hip/hip_bf16.h>
#include <hip/hip_fp16.h>

// DeepseekV4HashRouter: B=4,S=4096,D=2048,E=256,K=8,V=128000
#define DIM    2048
#define NEXP   256
#define TOPK   8
#define RSCALE 2.5f
#define WPT    4  // waves (tokens) per 256-thread block

typedef _Float16 h2 __attribute__((ext_vector_type(2)));

__device__ __forceinline__ float dot2(h2 a, h2 b, float c) {
#if __has_builtin(__builtin_amdgcn_fdot2)
    return __builtin_amdgcn_fdot2(a, b, c, false);
#else
    return c + (float)a[0] * (float)b[0] + (float)a[1] * (float)b[1];
#endif
}

__device__ __forceinline__ h2 cvt_pk(float x, float y) {
#if __has_builtin(__builtin_amdgcn_cvt_pkrtz)
    return __builtin_bit_cast(h2, __builtin_amdgcn_cvt_pkrtz(x, y));
#else
    h2 r; r[0] = (_Float16)x; r[1] = (_Float16)y; return r;
#endif
}

__device__ __forceinline__ h2 as_h2(unsigned int u) {
    return __builtin_bit_cast(h2, u);
}

__global__ __launch_bounds__(256) void convert_weight_f16(
    const float* __restrict__ w, unsigned int* __restrict__ wh, int n4) {
    int i = blockIdx.x * blockDim.x + threadIdx.x;  // over float4s
    if (i < n4) {
        float4 f = reinterpret_cast<const float4*>(w)[i];
        uint2 o;
        o.x = __builtin_bit_cast(unsigned int, cvt_pk(f.x, f.y));
        o.y = __builtin_bit_cast(unsigned int, cvt_pk(f.z, f.w));
        reinterpret_cast<uint2*>(wh)[i] = o;
    }
}

// One 64-lane wave per token; f16 weight, v_dot2, SGPR expert bases,
// j-outer loop for 8-wide independent load ILP.
template <bool F16W>
__global__ __launch_bounds__(256) void router_v4(
    const float* __restrict__ hidden,   // [N, D] fp32
    const int* __restrict__ token_ids,  // [N] int32
    const void* __restrict__ weight,    // [E, D] f16-pairs(u32) or fp32
    const int* __restrict__ tid2eid,    // [V, K] int32
    float* __restrict__ out,            // probs [N,E] then map [N,E]
    int N) {
    const int lane = threadIdx.x & 63;
    const int n = blockIdx.x * WPT + (threadIdx.x >> 6);
    if (n >= N) return;

    // token id / expert ids are wave-uniform -> force into SGPRs.
    const int tid = __builtin_amdgcn_readfirstlane(token_ids[n]);
    const int* er = tid2eid + (size_t)tid * TOPK;
    int eidx[TOPK];
#pragma unroll
    for (int k = 0; k < TOPK; ++k)
        eidx[k] = __builtin_amdgcn_readfirstlane(er[k]);

    const float4* h4 = reinterpret_cast<const float4*>(hidden + (size_t)n * DIM);

    float acc[TOPK] = {0.f, 0.f, 0.f, 0.f, 0.f, 0.f, 0.f, 0.f};

    if (F16W) {
        // SGPR base pointer per expert row; vaddr = lane*16 shared.
        const uint4* wb[TOPK];
#pragma unroll
        for (int k = 0; k < TOPK; ++k)
            wb[k] = reinterpret_cast<const uint4*>(weight) + (size_t)eidx[k] * (DIM / 8);

#pragma unroll
        for (int j = 0; j < 4; ++j) {
            // 8 independent weight loads (different SGPR base, imm offset j*1024B).
            uint4 wv[TOPK];
#pragma unroll
            for (int k = 0; k < TOPK; ++k) wv[k] = wb[k][j * 64 + lane];
            // this lane's 8 hidden floats for chunk j, packed to 4 f16-pairs
            const float4 a = h4[j * 128 + lane * 2];
            const float4 b = h4[j * 128 + lane * 2 + 1];
            const h2 h0 = cvt_pk(a.x, a.y), h1 = cvt_pk(a.z, a.w);
            const h2 g0 = cvt_pk(b.x, b.y), g1 = cvt_pk(b.z, b.w);
#pragma unroll
            for (int k = 0; k < TOPK; ++k) {
                acc[k] = dot2(h0, as_h2(wv[k].x), acc[k]);
                acc[k] = dot2(h1, as_h2(wv[k].y), acc[k]);
                acc[k] = dot2(g0, as_h2(wv[k].z), acc[k]);
                acc[k] = dot2(g1, as_h2(wv[k].w), acc[k]);
            }
        }
    } else {
        const float* wf = reinterpret_cast<const float*>(weight);
#pragma unroll
        for (int j = 0; j < 4; ++j) {
            const float4 a = h4[j * 128 + lane * 2];
            const float4 b = h4[j * 128 + lane * 2 + 1];
#pragma unroll
            for (int k = 0; k < TOPK; ++k) {
                const float4* wrow = reinterpret_cast<const float4*>(wf + (size_t)eidx[k] * DIM);
                const float4 wa = wrow[j * 128 + lane * 2];
                const float4 wbv = wrow[j * 128 + lane * 2 + 1];
                acc[k] += a.x * wa.x + a.y * wa.y + a.z * wa.z + a.w * wa.w
                        + b.x * wbv.x + b.y * wbv.y + b.z * wbv.z + b.w * wbv.w;
            }
        }
    }

    // Tournament reduce: 8 values/lane -> 1 value/lane in 7 shfls + 3 butterfly.
    const int b0 = lane & 1, b1 = (lane >> 1) & 1, b2 = (lane >> 2) & 1;
    float v4[4];
#pragma unroll
    for (int k = 0; k < 4; ++k) {
        const float send = b0 ? acc[k] : acc[k + 4];
        const float recv = __shfl_xor(send, 1, 64);
        v4[k] = (b0 ? acc[k + 4] : acc[k]) + recv;
    }
    float v2[2];
#pragma unroll
    for (int j = 0; j < 2; ++j) {
        const float send = b1 ? v4[j] : v4[j + 2];
        const float recv = __shfl_xor(send, 2, 64);
        v2[j] = (b1 ? v4[j + 2] : v4[j]) + recv;
    }
    {
        const float send = b2 ? v2[0] : v2[1];
        const float recv = __shfl_xor(send, 4, 64);
        v2[0] = (b2 ? v2[1] : v2[0]) + recv;
    }
    float v = v2[0];
    v += __shfl_xor(v, 8, 64);
    v += __shfl_xor(v, 16, 64);
    v += __shfl_xor(v, 32, 64);
    // Lane l holds logit of expert slot e(l) = 4*b0 + 2*b1 + b2.

    const float sp = fmaxf(v, 0.0f) + log1pf(expf(-fabsf(v)));
    const float score = sqrtf(sp);

    // Slot k lives in lane bit-rev3(k).
    float sc[TOPK];
    float denom = 0.0f;
#pragma unroll
    for (int k = 0; k < TOPK; ++k) {
        const int src = ((k >> 2) & 1) | (k & 2) | ((k & 1) << 2);
        sc[k] = __shfl(score, src, 64);
        denom += sc[k];
    }
    const float inv = RSCALE / fmaxf(denom, 1e-12f);

    // Dense vectorized write: lane l owns experts 4l..4l+3.
    float4 p, m;
    float* pp = reinterpret_cast<float*>(&p);
    float* mm = reinterpret_cast<float*>(&m);
#pragma unroll
    for (int c = 0; c < 4; ++c) {
        const int e = lane * 4 + c;
        float pv = 0.0f, mv = 0.0f;
#pragma unroll
        for (int k = 0; k < TOPK; ++k) {
            if (eidx[k] == e) { pv = sc[k] * inv; mv = 1.0f; }
        }
        pp[c] = pv; mm[c] = mv;
    }
    reinterpret_cast<float4*>(out + (size_t)n * NEXP)[lane] = p;
    reinterpret_cast<float4*>(out + (size_t)(N + n) * NEXP)[lane] = m;
}

extern "C" void kernel_launch(void* const* d_in, const int* in_sizes, int n_in,
                              void* d_out, int out_size, void* d_ws, size_t ws_size,
                              hipStream_t stream) {
    const float* hidden    = (const float*)d_in[0];
    const int*   token_ids = (const int*)d_in[1];   // int64 in ref -> int32 here
    const float* weight    = (const float*)d_in[2];
    const int*   tid2eid   = (const int*)d_in[3];
    float* out = (float*)d_out;
    const int N = in_sizes[1];  // B*S tokens

    const int nblocks = (N + WPT - 1) / WPT;
    const size_t need = (size_t)NEXP * DIM * sizeof(unsigned short);  // 1 MiB
    if (ws_size >= need) {
        unsigned int* wh = (unsigned int*)d_ws;
        const int n4 = NEXP * DIM / 4;
        convert_weight_f16<<<(n4 + 255) / 256, 256, 0, stream>>>(weight, wh, n4);
        router_v4<true><<<nblocks, 256, 0, stream>>>(hidden, token_ids, wh, tid2eid, out, N);
    } else {
        router_v4<false><<<nblocks, 256, 0, stream>>>(hidden, token_ids, weight, tid2eid, out, N);
    }
}